// Round 1
// baseline (740.483 us; speedup 1.0000x reference)
//
#include <hip/hip_runtime.h>
#include <hip/hip_bf16.h>

// Problem constants (from reference): B=4, S=1024, D=1024, H=4096, E=8, K=2
#define DIM_D 1024
#define DIM_H 4096
#define NUM_E 8
#define NUM_TOK 4096           // B*S
#define MAXROWS 8320           // <= 2*NUM_TOK assignments + 128 tile padding

typedef __attribute__((ext_vector_type(8))) short short8;
typedef __attribute__((ext_vector_type(4))) float floatx4;

__device__ __forceinline__ unsigned short f2bf(float f) {
  union { float f; unsigned int u; } v; v.f = f;
  unsigned int r = v.u + 0x7fffu + ((v.u >> 16) & 1u);   // round-to-nearest-even
  return (unsigned short)(r >> 16);
}

__device__ __forceinline__ void async_copy16(const void* g, void* l) {
  __builtin_amdgcn_global_load_lds(
      (__attribute__((address_space(1))) unsigned int*)(g),
      (__attribute__((address_space(3))) unsigned int*)(l), 16, 0, 0);
}

// ---------------- routing ----------------

__global__ void route_count(const int* __restrict__ assign, int* __restrict__ counts) {
  int t = blockIdx.x * blockDim.x + threadIdx.x;
  if (t < NUM_TOK) {
    int e0 = assign[2 * t], e1 = assign[2 * t + 1];
    atomicAdd(&counts[e0], 1);
    if (e1 != e0) atomicAdd(&counts[e1], 1);
  }
}

__global__ void scan_k(const int* __restrict__ counts, int* __restrict__ offsets,
                       int* __restrict__ cursors) {
  if (threadIdx.x == 0 && blockIdx.x == 0) {
    int acc = 0;
    for (int e = 0; e < NUM_E; e++) {
      offsets[e] = acc; cursors[e] = acc; acc += counts[e];
    }
  }
}

// one block per token: claim row slots, convert x row fp32->bf16, scatter to Xg
__global__ void gather_k(const float* __restrict__ x, const int* __restrict__ assign,
                         int* __restrict__ cursors, int* __restrict__ rowtok,
                         unsigned short* __restrict__ Xg) {
  int t = blockIdx.x;
  __shared__ int sr[2];
  if (threadIdx.x == 0) {
    int e0 = assign[2 * t], e1 = assign[2 * t + 1];
    int r0 = atomicAdd(&cursors[e0], 1);
    int r1 = (e1 != e0) ? atomicAdd(&cursors[e1], 1) : -1;
    rowtok[r0] = t;
    if (r1 >= 0) rowtok[r1] = t;
    sr[0] = r0; sr[1] = r1;
  }
  __syncthreads();
  int r0 = sr[0], r1 = sr[1];
  const float4* xv = (const float4*)(x + (size_t)t * DIM_D);
  float4 v0 = xv[threadIdx.x * 2];
  float4 v1 = xv[threadIdx.x * 2 + 1];
  unsigned short h[8];
  h[0] = f2bf(v0.x); h[1] = f2bf(v0.y); h[2] = f2bf(v0.z); h[3] = f2bf(v0.w);
  h[4] = f2bf(v1.x); h[5] = f2bf(v1.y); h[6] = f2bf(v1.z); h[7] = f2bf(v1.w);
  uint4 pack = *(uint4*)h;
  *(uint4*)(Xg + (size_t)r0 * DIM_D + threadIdx.x * 8) = pack;
  if (r1 >= 0)
    *(uint4*)(Xg + (size_t)r1 * DIM_D + threadIdx.x * 8) = pack;
}

// ---------------- weight transpose + fp32->bf16 ----------------
// in: fp32 [E][R][C]  ->  out: bf16 [E][C][R]
__global__ void transpose_cvt(const float* __restrict__ in, unsigned short* __restrict__ outp,
                              int R, int C) {
  __shared__ float tile[64][65];
  int e = blockIdx.z;
  const float* ip = in + (size_t)e * R * C + (size_t)(blockIdx.y * 64) * C + blockIdx.x * 64;
  unsigned short* op = outp + (size_t)e * R * C + (size_t)(blockIdx.x * 64) * R + blockIdx.y * 64;
  int rr = threadIdx.x >> 4;            // 0..15
  int c4 = (threadIdx.x & 15) * 4;      // 0..60
#pragma unroll
  for (int i = 0; i < 4; i++) {
    int r = rr + i * 16;
    float4 v = *(const float4*)(ip + (size_t)r * C + c4);
    tile[r][c4 + 0] = v.x; tile[r][c4 + 1] = v.y;
    tile[r][c4 + 2] = v.z; tile[r][c4 + 3] = v.w;
  }
  __syncthreads();
  int cc = threadIdx.x >> 4;
  int r4 = (threadIdx.x & 15) * 4;
#pragma unroll
  for (int i = 0; i < 4; i++) {
    int c = cc + i * 16;
    ushort4 o;
    o.x = f2bf(tile[r4 + 0][c]); o.y = f2bf(tile[r4 + 1][c]);
    o.z = f2bf(tile[r4 + 2][c]); o.w = f2bf(tile[r4 + 3][c]);
    *(ushort4*)(op + (size_t)c * R + r4) = o;
  }
}

// ---------------- grouped GEMM (m97 structure) ----------------
// C[m,n] = sum_k A[rowbase+m, k] * Bt[e][n][k]
// MODE 0: Hout[rowbase+m, n] = bf16(relu(C + bias[e][n]))
// MODE 1: atomicAdd(Fout[rowtok[rowbase+m]*N + n], (C + bias[e][n]) * (1/k))
template <int MODE>
__global__ __launch_bounds__(256) void moe_gemm(
    const unsigned short* __restrict__ A, const unsigned short* __restrict__ Bt,
    const float* __restrict__ bias, const int* __restrict__ counts,
    const int* __restrict__ offsets, const int* __restrict__ rowtok,
    unsigned short* __restrict__ Hout, float* __restrict__ Fout,
    const int* __restrict__ kptr, int K, int N) {
  const int e = blockIdx.z;
  const int cnt = counts[e];
  const int m0 = blockIdx.y * 128;
  if (m0 >= cnt) return;
  const int n0 = blockIdx.x * 128;
  const int rowbase = offsets[e];

  __shared__ unsigned short As[128 * 32];  // [m][k] K-major
  __shared__ unsigned short Bs[128 * 32];  // [n][k] K-major

  const int tid = threadIdx.x;
  const int w = tid >> 6;         // wave 0..3
  const int lane = tid & 63;
  const int l15 = lane & 15, l4 = lane >> 4;
  const int wm = w >> 1, wn = w & 1;

  // staging: 2 x 16B insts per thread per operand; rows 0..63 then 64..127
  const int srow = tid >> 2;      // 0..63
  const int schunk = tid & 3;
  const unsigned short* gA0 = A + (size_t)(rowbase + m0 + srow) * K + schunk * 8;
  const unsigned short* gA1 = gA0 + (size_t)64 * K;
  const unsigned short* gB0 = Bt + (size_t)e * N * K + (size_t)(n0 + srow) * K + schunk * 8;
  const unsigned short* gB1 = gB0 + (size_t)64 * K;
  char* lA = (char*)As;
  char* lB = (char*)Bs;
  void* dA0 = lA + w * 1024;          // wave-uniform LDS base
  void* dA1 = lA + 4096 + w * 1024;
  void* dB0 = lB + w * 1024;
  void* dB1 = lB + 4096 + w * 1024;

  floatx4 acc[4][4];
#pragma unroll
  for (int i = 0; i < 4; i++)
#pragma unroll
    for (int j = 0; j < 4; j++) acc[i][j] = (floatx4){0.f, 0.f, 0.f, 0.f};

  int aidx[4], bidx[4];
#pragma unroll
  for (int mt = 0; mt < 4; mt++) aidx[mt] = (wm * 64 + mt * 16 + l15) * 32 + l4 * 8;
#pragma unroll
  for (int nt = 0; nt < 4; nt++) bidx[nt] = (wn * 64 + nt * 16 + l15) * 32 + l4 * 8;

  for (int k0 = 0; k0 < K; k0 += 32) {
    __syncthreads();
    async_copy16(gA0, dA0);
    async_copy16(gA1, dA1);
    async_copy16(gB0, dB0);
    async_copy16(gB1, dB1);
    gA0 += 32; gA1 += 32; gB0 += 32; gB1 += 32;
    __syncthreads();
    short8 a[4], b[4];
#pragma unroll
    for (int mt = 0; mt < 4; mt++) a[mt] = *(const short8*)(As + aidx[mt]);
#pragma unroll
    for (int nt = 0; nt < 4; nt++) b[nt] = *(const short8*)(Bs + bidx[nt]);
#pragma unroll
    for (int mt = 0; mt < 4; mt++)
#pragma unroll
      for (int nt = 0; nt < 4; nt++)
        acc[mt][nt] = __builtin_amdgcn_mfma_f32_16x16x32_bf16(a[mt], b[nt], acc[mt][nt], 0, 0, 0);
  }

  const float* be = bias + (size_t)e * N;
  if (MODE == 0) {
#pragma unroll
    for (int mt = 0; mt < 4; mt++) {
      int gmb = m0 + wm * 64 + mt * 16 + l4 * 4;
#pragma unroll
      for (int r = 0; r < 4; r++) {
        int gm = gmb + r;
        if (gm < cnt) {
          size_t rowoff = (size_t)(rowbase + gm) * N;
#pragma unroll
          for (int nt = 0; nt < 4; nt++) {
            int n = n0 + wn * 64 + nt * 16 + l15;
            float v = acc[mt][nt][r] + be[n];
            Hout[rowoff + n] = f2bf(fmaxf(v, 0.f));
          }
        }
      }
    }
  } else {
    float invk = 1.0f / (float)kptr[0];
#pragma unroll
    for (int mt = 0; mt < 4; mt++) {
      int gmb = m0 + wm * 64 + mt * 16 + l4 * 4;
#pragma unroll
      for (int r = 0; r < 4; r++) {
        int gm = gmb + r;
        if (gm < cnt) {
          int tok = rowtok[rowbase + gm];
          size_t obase = (size_t)tok * N;
#pragma unroll
          for (int nt = 0; nt < 4; nt++) {
            int n = n0 + wn * 64 + nt * 16 + l15;
            atomicAdd(&Fout[obase + n], (acc[mt][nt][r] + be[n]) * invk);
          }
        }
      }
    }
  }
}

// ---------------- launch ----------------

extern "C" void kernel_launch(void* const* d_in, const int* in_sizes, int n_in,
                              void* d_out, int out_size, void* d_ws, size_t ws_size,
                              hipStream_t stream) {
  const float* x = (const float*)d_in[0];
  const float* W1 = (const float*)d_in[1];
  const float* b1 = (const float*)d_in[2];
  const float* W2 = (const float*)d_in[3];
  const float* b2 = (const float*)d_in[4];
  const int* assign = (const int*)d_in[5];
  const int* kptr = (const int*)d_in[6];
  float* out = (float*)d_out;

  // workspace carve-up
  char* p = (char*)d_ws;
  int* counts = (int*)p; p += 256;
  int* offsets = (int*)p; p += 256;
  int* cursors = (int*)p; p += 256;
  int* rowtok = (int*)p; p += ((MAXROWS * 4 + 255) / 256) * 256;
  unsigned short* Xg = (unsigned short*)p; p += (size_t)MAXROWS * DIM_D * 2;   // 17 MB
  unsigned short* Hg = (unsigned short*)p; p += (size_t)MAXROWS * DIM_H * 2;   // 68 MB
  unsigned short* W1t = (unsigned short*)p; p += (size_t)NUM_E * DIM_D * DIM_H * 2; // 64 MB
  unsigned short* W2t = (unsigned short*)p; p += (size_t)NUM_E * DIM_D * DIM_H * 2; // 64 MB

  hipMemsetAsync(counts, 0, 256, stream);
  hipMemsetAsync(d_out, 0, (size_t)out_size * sizeof(float), stream);

  route_count<<<(NUM_TOK + 255) / 256, 256, 0, stream>>>(assign, counts);
  scan_k<<<1, 64, 0, stream>>>(counts, offsets, cursors);
  gather_k<<<NUM_TOK, 128, 0, stream>>>(x, assign, cursors, rowtok, Xg);

  // W1 [E][D][H] -> W1t [E][H][D] ; W2 [E][H][D] -> W2t [E][D][H]
  transpose_cvt<<<dim3(DIM_H / 64, DIM_D / 64, NUM_E), 256, 0, stream>>>(W1, W1t, DIM_D, DIM_H);
  transpose_cvt<<<dim3(DIM_D / 64, DIM_H / 64, NUM_E), 256, 0, stream>>>(W2, W2t, DIM_H, DIM_D);

  // GEMM1: h = relu(Xg @ W1 + b1)  -> Hg bf16   (M<=4096/expert, N=H, K=D)
  moe_gemm<0><<<dim3(DIM_H / 128, 32, NUM_E), 256, 0, stream>>>(
      Xg, W1t, b1, counts, offsets, nullptr, Hg, nullptr, nullptr, DIM_D, DIM_H);
  // GEMM2: out += (Hg @ W2 + b2)/k  (M<=4096/expert, N=D, K=H)
  moe_gemm<1><<<dim3(DIM_D / 128, 32, NUM_E), 256, 0, stream>>>(
      Hg, W2t, b2, counts, offsets, rowtok, nullptr, out, kptr, DIM_H, DIM_D);
}

// Round 2
// 656.236 us; speedup vs baseline: 1.1284x; 1.1284x over previous
//
#include <hip/hip_runtime.h>
#include <hip/hip_bf16.h>

// Problem constants: B=4, S=1024, D=1024, H=4096, E=8, K=2
#define DIM_D 1024
#define DIM_H 4096
#define NUM_E 8
#define NUM_TOK 4096
#define MAXROWS 8320           // 2*NUM_TOK assignments + tile padding

typedef __attribute__((ext_vector_type(8))) short short8;
typedef __attribute__((ext_vector_type(4))) float floatx4;

__device__ __forceinline__ unsigned short f2bf(float f) {
  union { float f; unsigned int u; } v; v.f = f;
  unsigned int r = v.u + 0x7fffu + ((v.u >> 16) & 1u);   // RNE
  return (unsigned short)(r >> 16);
}

__device__ __forceinline__ void async_copy16(const void* g, void* l) {
  __builtin_amdgcn_global_load_lds(
      (__attribute__((address_space(1))) unsigned int*)(g),
      (__attribute__((address_space(3))) unsigned int*)(l), 16, 0, 0);
}

// ---------------- routing ----------------

__global__ void route_count(const int* __restrict__ assign, int* __restrict__ counts) {
  int t = blockIdx.x * blockDim.x + threadIdx.x;
  if (t < NUM_TOK) {
    int e0 = assign[2 * t], e1 = assign[2 * t + 1];
    atomicAdd(&counts[e0], 1);
    if (e1 != e0) atomicAdd(&counts[e1], 1);
  }
}

__global__ void scan_k(const int* __restrict__ counts, int* __restrict__ offsets,
                       int* __restrict__ cursors) {
  if (threadIdx.x == 0 && blockIdx.x == 0) {
    int acc = 0;
    for (int e = 0; e < NUM_E; e++) {
      offsets[e] = acc; cursors[e] = acc; acc += counts[e];
    }
  }
}

// one block per token: claim row slots, convert x row fp32->bf16, scatter to Xg
__global__ void gather_k(const float* __restrict__ x, const int* __restrict__ assign,
                         int* __restrict__ cursors, int* __restrict__ tok2row,
                         unsigned short* __restrict__ Xg) {
  int t = blockIdx.x;
  __shared__ int sr[2];
  if (threadIdx.x == 0) {
    int e0 = assign[2 * t], e1 = assign[2 * t + 1];
    int r0 = atomicAdd(&cursors[e0], 1);
    int r1 = (e1 != e0) ? atomicAdd(&cursors[e1], 1) : -1;
    tok2row[2 * t] = r0; tok2row[2 * t + 1] = r1;
    sr[0] = r0; sr[1] = r1;
  }
  __syncthreads();
  int r0 = sr[0], r1 = sr[1];
  const float4* xv = (const float4*)(x + (size_t)t * DIM_D);
  float4 v0 = xv[threadIdx.x * 2];
  float4 v1 = xv[threadIdx.x * 2 + 1];
  unsigned short h[8];
  h[0] = f2bf(v0.x); h[1] = f2bf(v0.y); h[2] = f2bf(v0.z); h[3] = f2bf(v0.w);
  h[4] = f2bf(v1.x); h[5] = f2bf(v1.y); h[6] = f2bf(v1.z); h[7] = f2bf(v1.w);
  uint4 pack = *(uint4*)h;
  *(uint4*)(Xg + (size_t)r0 * DIM_D + threadIdx.x * 8) = pack;
  if (r1 >= 0)
    *(uint4*)(Xg + (size_t)r1 * DIM_D + threadIdx.x * 8) = pack;
}

// ---------------- weight transpose + fp32->bf16 ----------------
// in: fp32 [E][R][C]  ->  out: bf16 [E][C][R]
__global__ void transpose_cvt(const float* __restrict__ in, unsigned short* __restrict__ outp,
                              int R, int C) {
  __shared__ float tile[64][65];
  int e = blockIdx.z;
  const float* ip = in + (size_t)e * R * C + (size_t)(blockIdx.y * 64) * C + blockIdx.x * 64;
  unsigned short* op = outp + (size_t)e * R * C + (size_t)(blockIdx.x * 64) * R + blockIdx.y * 64;
  int rr = threadIdx.x >> 4;            // 0..15
  int c4 = (threadIdx.x & 15) * 4;      // 0..60
#pragma unroll
  for (int i = 0; i < 4; i++) {
    int r = rr + i * 16;
    float4 v = *(const float4*)(ip + (size_t)r * C + c4);
    tile[r][c4 + 0] = v.x; tile[r][c4 + 1] = v.y;
    tile[r][c4 + 2] = v.z; tile[r][c4 + 3] = v.w;
  }
  __syncthreads();
  int r8 = (threadIdx.x & 7) * 8;
  int cbase = threadIdx.x >> 3;         // 0..31
#pragma unroll
  for (int it = 0; it < 2; it++) {
    int c = cbase + it * 32;
    unsigned short h[8];
#pragma unroll
    for (int j = 0; j < 8; j++) h[j] = f2bf(tile[r8 + j][c]);
    *(uint4*)(op + (size_t)c * R + r8) = *(const uint4*)h;   // 16B store
  }
}

// ---------------- grouped GEMM, BK=64, XOR-swizzled LDS ----------------
// C[m,n] = sum_k A[rowbase+m, k] * Bt[e][n][k]
// MODE 0: Hout[rowbase+m, n] = bf16(relu(C + bias[e][n]))   (XCD-aware remap)
// MODE 1: Yout[rowbase+m, n] = C + bias[e][n]               (fp32, combined later)
template <int MODE>
__global__ __launch_bounds__(256) void moe_gemm(
    const unsigned short* __restrict__ A, const unsigned short* __restrict__ Bt,
    const float* __restrict__ bias, const int* __restrict__ counts,
    const int* __restrict__ offsets,
    unsigned short* __restrict__ Hout, float* __restrict__ Yout,
    int K, int N) {
  const int e = blockIdx.z;
  const int cnt = counts[e];
  int mt_, nt_;
  if (MODE == 0) {
    // remap so XCD (~gid%8 = x&7) keeps a small set of B n-tiles L2-resident
    nt_ = (blockIdx.x & 7) | ((blockIdx.y & 3) << 3);
    mt_ = (blockIdx.x >> 3) | ((blockIdx.y >> 2) << 2);
  } else {
    nt_ = blockIdx.x; mt_ = blockIdx.y;
  }
  const int m0 = mt_ * 128;
  if (m0 >= cnt) return;
  const int n0 = nt_ * 128;
  const int rowbase = offsets[e];

  __shared__ unsigned short sh[2 * 128 * 64];   // As | Bs, 32 KB, rows of 64 elems (128B)
  unsigned short* As = sh;
  unsigned short* Bs = sh + 128 * 64;

  const int tid = threadIdx.x;
  const int w = tid >> 6;
  const int lane = tid & 63;
  const int l15 = lane & 15, l4 = lane >> 4;
  const int wm = w >> 1, wn = w & 1;
  const int lrow = lane >> 3, lslot = lane & 7;
  const int lchunk = lslot ^ lrow;   // XOR swizzle: LDS slot s' of row r holds global chunk s'^(r&7)

  const unsigned short* gA[4]; const unsigned short* gB[4];
  void* dA[4]; void* dB[4];
  const unsigned short* Bbase = Bt + (size_t)e * N * K;
#pragma unroll
  for (int p = 0; p < 4; p++) {
    int rw = p * 32 + w * 8;          // 8 rows per wave per round
    gA[p] = A + (size_t)(rowbase + m0 + rw + lrow) * K + lchunk * 8;
    gB[p] = Bbase + (size_t)(n0 + rw + lrow) * K + lchunk * 8;
    dA[p] = (char*)As + rw * 128;     // wave-uniform LDS base
    dB[p] = (char*)Bs + rw * 128;
  }

  floatx4 acc[4][4];
#pragma unroll
  for (int i = 0; i < 4; i++)
#pragma unroll
    for (int j = 0; j < 4; j++) acc[i][j] = (floatx4){0.f, 0.f, 0.f, 0.f};

  int arow[4], brow[4], sl[2];
  sl[0] = ((l4 + 0) ^ (l15 & 7)) * 8;    // de-swizzled slot for k-chunk l4
  sl[1] = ((l4 + 4) ^ (l15 & 7)) * 8;    // ... for k-chunk l4+4 (second half of BK=64)
#pragma unroll
  for (int mt = 0; mt < 4; mt++) arow[mt] = (wm * 64 + mt * 16 + l15) * 64;
#pragma unroll
  for (int nt = 0; nt < 4; nt++) brow[nt] = (wn * 64 + nt * 16 + l15) * 64;

  for (int k0 = 0; k0 < K; k0 += 64) {
    __syncthreads();
#pragma unroll
    for (int p = 0; p < 4; p++) async_copy16(gA[p], dA[p]);
#pragma unroll
    for (int p = 0; p < 4; p++) async_copy16(gB[p], dB[p]);
#pragma unroll
    for (int p = 0; p < 4; p++) { gA[p] += 64; gB[p] += 64; }
    __syncthreads();
#pragma unroll
    for (int s = 0; s < 2; s++) {
      short8 a[4], b[4];
#pragma unroll
      for (int mt = 0; mt < 4; mt++) a[mt] = *(const short8*)(As + arow[mt] + sl[s]);
#pragma unroll
      for (int nt = 0; nt < 4; nt++) b[nt] = *(const short8*)(Bs + brow[nt] + sl[s]);
#pragma unroll
      for (int mt = 0; mt < 4; mt++)
#pragma unroll
        for (int nt = 0; nt < 4; nt++)
          acc[mt][nt] = __builtin_amdgcn_mfma_f32_16x16x32_bf16(a[mt], b[nt], acc[mt][nt], 0, 0, 0);
    }
  }

  // ---- epilogue: per-wave LDS transpose -> 16B-segment vector stores ----
  __syncthreads();                        // all waves done reading As/Bs
  float* sbuf = (float*)sh + w * 1088;    // 16 x 68 fp32 per wave (17 KB total)
  const float* be = bias + (size_t)e * N + n0 + wn * 64;
#pragma unroll
  for (int mt = 0; mt < 4; mt++) {
#pragma unroll
    for (int nt = 0; nt < 4; nt++) {
      float bv = be[nt * 16 + l15];
#pragma unroll
      for (int r = 0; r < 4; r++) {
        float v = acc[mt][nt][r] + bv;
        if (MODE == 0) v = fmaxf(v, 0.f);
        sbuf[(l4 * 4 + r) * 68 + nt * 16 + l15] = v;   // C layout: row=l4*4+r, col=nt*16+l15
      }
    }
    __syncthreads();                      // writes visible before transposed reads
#pragma unroll
    for (int pass = 0; pass < 4; pass++) {
      int row = pass * 4 + l4;
      int col4 = l15 * 4;
      int gm = m0 + wm * 64 + mt * 16 + row;
      float4 v = *(const float4*)&sbuf[row * 68 + col4];
      if (gm < cnt) {
        size_t off = (size_t)(rowbase + gm) * N + n0 + wn * 64 + col4;
        if (MODE == 0) {
          ushort4 h;
          h.x = f2bf(v.x); h.y = f2bf(v.y); h.z = f2bf(v.z); h.w = f2bf(v.w);
          *(ushort4*)(Hout + off) = h;
        } else {
          *(float4*)(Yout + off) = v;
        }
      }
    }
    __syncthreads();                      // reads done before next mt overwrites
  }
}

// ---------------- combine: out[t] = (Y[r0] (+ Y[r1])) / k ----------------
__global__ void combine_k(const float* __restrict__ Yg, const int* __restrict__ tok2row,
                          const int* __restrict__ kptr, float* __restrict__ out) {
  int t = blockIdx.x;
  int r0 = tok2row[2 * t], r1 = tok2row[2 * t + 1];
  float invk = 1.0f / (float)kptr[0];
  int d = threadIdx.x * 4;
  float4 v = *(const float4*)(Yg + (size_t)r0 * DIM_D + d);
  if (r1 >= 0) {
    float4 u = *(const float4*)(Yg + (size_t)r1 * DIM_D + d);
    v.x += u.x; v.y += u.y; v.z += u.z; v.w += u.w;
  }
  float4 o; o.x = v.x * invk; o.y = v.y * invk; o.z = v.z * invk; o.w = v.w * invk;
  *(float4*)(out + (size_t)t * DIM_D + d) = o;
}

// ---------------- launch ----------------

extern "C" void kernel_launch(void* const* d_in, const int* in_sizes, int n_in,
                              void* d_out, int out_size, void* d_ws, size_t ws_size,
                              hipStream_t stream) {
  const float* x = (const float*)d_in[0];
  const float* W1 = (const float*)d_in[1];
  const float* b1 = (const float*)d_in[2];
  const float* W2 = (const float*)d_in[3];
  const float* b2 = (const float*)d_in[4];
  const int* assign = (const int*)d_in[5];
  const int* kptr = (const int*)d_in[6];
  float* out = (float*)d_out;

  char* p = (char*)d_ws;
  int* counts = (int*)p; p += 256;
  int* offsets = (int*)p; p += 256;
  int* cursors = (int*)p; p += 256;
  int* tok2row = (int*)p; p += NUM_TOK * 2 * 4;                                // 32 KB
  unsigned short* Xg = (unsigned short*)p; p += (size_t)MAXROWS * DIM_D * 2;   // 17 MB
  unsigned short* Hg = (unsigned short*)p; p += (size_t)MAXROWS * DIM_H * 2;   // 68 MB
  unsigned short* W1t = (unsigned short*)p; p += (size_t)NUM_E * DIM_D * DIM_H * 2; // 64 MB
  unsigned short* W2t = (unsigned short*)p; p += (size_t)NUM_E * DIM_D * DIM_H * 2; // 64 MB
  // Yg aliases W1t: GEMM1 (reader of W1t) completes before GEMM2 writes Yg
  float* Yg = (float*)W1t;                // needs MAXROWS*DIM_D*4 = 34 MB <= 64 MB

  hipMemsetAsync(counts, 0, 256, stream);

  route_count<<<(NUM_TOK + 255) / 256, 256, 0, stream>>>(assign, counts);
  scan_k<<<1, 64, 0, stream>>>(counts, offsets, cursors);
  gather_k<<<NUM_TOK, 128, 0, stream>>>(x, assign, cursors, tok2row, Xg);

  // W1 [E][D][H] -> W1t [E][H][D] ; W2 [E][H][D] -> W2t [E][D][H]
  transpose_cvt<<<dim3(DIM_H / 64, DIM_D / 64, NUM_E), 256, 0, stream>>>(W1, W1t, DIM_D, DIM_H);
  transpose_cvt<<<dim3(DIM_D / 64, DIM_H / 64, NUM_E), 256, 0, stream>>>(W2, W2t, DIM_H, DIM_D);

  // GEMM1: Hg = relu(Xg @ W1 + b1)  (K=D, N=H)
  moe_gemm<0><<<dim3(DIM_H / 128, 32, NUM_E), 256, 0, stream>>>(
      Xg, W1t, b1, counts, offsets, Hg, nullptr, DIM_D, DIM_H);
  // GEMM2: Yg = Hg @ W2 + b2        (K=H, N=D)
  moe_gemm<1><<<dim3(DIM_D / 128, 32, NUM_E), 256, 0, stream>>>(
      Hg, W2t, b2, counts, offsets, nullptr, Yg, DIM_H, DIM_D);

  combine_k<<<NUM_TOK, 256, 0, stream>>>(Yg, tok2row, kptr, out);
}

// Round 3
// 634.218 us; speedup vs baseline: 1.1676x; 1.0347x over previous
//
#include <hip/hip_runtime.h>
#include <hip/hip_bf16.h>

// Problem constants: B=4, S=1024, D=1024, H=4096, E=8, K=2
#define DIM_D 1024
#define DIM_H 4096
#define NUM_E 8
#define NUM_TOK 4096
#define MAXROWS 8320           // 2*NUM_TOK assignments + tile overrun pad

typedef __attribute__((ext_vector_type(8))) short short8;
typedef __attribute__((ext_vector_type(4))) float floatx4;

__device__ __forceinline__ unsigned short f2bf(float f) {
  union { float f; unsigned int u; } v; v.f = f;
  unsigned int r = v.u + 0x7fffu + ((v.u >> 16) & 1u);   // RNE
  return (unsigned short)(r >> 16);
}

__device__ __forceinline__ void async_copy16(const void* g, void* l) {
  __builtin_amdgcn_global_load_lds(
      (__attribute__((address_space(1))) unsigned int*)(g),
      (__attribute__((address_space(3))) unsigned int*)(l), 16, 0, 0);
}

// ---------------- routing: histogram + scan in one block ----------------

__global__ void route_scan(const int* __restrict__ assign, int* __restrict__ counts,
                           int* __restrict__ offsets, int* __restrict__ cursors) {
  __shared__ int hist[NUM_E];
  int tid = threadIdx.x;
  if (tid < NUM_E) hist[tid] = 0;
  __syncthreads();
  for (int t = tid; t < NUM_TOK; t += 256) {
    int e0 = assign[2 * t], e1 = assign[2 * t + 1];
    atomicAdd(&hist[e0], 1);
    if (e1 != e0) atomicAdd(&hist[e1], 1);
  }
  __syncthreads();
  if (tid == 0) {
    int acc = 0;
    for (int e = 0; e < NUM_E; e++) {
      counts[e] = hist[e]; offsets[e] = acc; cursors[e] = acc; acc += hist[e];
    }
  }
}

// one block per token: claim row slots, convert x row fp32->bf16, scatter to Xg
__global__ void gather_k(const float* __restrict__ x, const int* __restrict__ assign,
                         int* __restrict__ cursors, int* __restrict__ tok2row,
                         unsigned short* __restrict__ Xg) {
  int t = blockIdx.x;
  __shared__ int sr[2];
  if (threadIdx.x == 0) {
    int e0 = assign[2 * t], e1 = assign[2 * t + 1];
    int r0 = atomicAdd(&cursors[e0], 1);
    int r1 = (e1 != e0) ? atomicAdd(&cursors[e1], 1) : -1;
    tok2row[2 * t] = r0; tok2row[2 * t + 1] = r1;
    sr[0] = r0; sr[1] = r1;
  }
  __syncthreads();
  int r0 = sr[0], r1 = sr[1];
  const float4* xv = (const float4*)(x + (size_t)t * DIM_D);
  float4 v0 = xv[threadIdx.x * 2];
  float4 v1 = xv[threadIdx.x * 2 + 1];
  unsigned short h[8];
  h[0] = f2bf(v0.x); h[1] = f2bf(v0.y); h[2] = f2bf(v0.z); h[3] = f2bf(v0.w);
  h[4] = f2bf(v1.x); h[5] = f2bf(v1.y); h[6] = f2bf(v1.z); h[7] = f2bf(v1.w);
  uint4 pack = *(uint4*)h;
  *(uint4*)(Xg + (size_t)r0 * DIM_D + threadIdx.x * 8) = pack;
  if (r1 >= 0)
    *(uint4*)(Xg + (size_t)r1 * DIM_D + threadIdx.x * 8) = pack;
}

// ------------- both weight transposes fused, fp32->bf16, 256B write segs -------------
// z = e*2 + which. which=0: W1 [D][H] -> W1t [H][D]; which=1: W2 [H][D] -> W2t [D][H]
__global__ __launch_bounds__(256) void transpose_cvt2(
    const float* __restrict__ W1, const float* __restrict__ W2,
    unsigned short* __restrict__ W1t, unsigned short* __restrict__ W2t) {
  __shared__ float tile[128][33];
  const int z = blockIdx.y;
  const int e = z >> 1, which = z & 1;
  const int R = which ? DIM_H : DIM_D;     // source rows
  const int C = which ? DIM_D : DIM_H;     // source cols
  const int nbx = C / 32;
  const int bx = blockIdx.x % nbx;
  const int by = blockIdx.x / nbx;
  const float* ip = (which ? W2 : W1) + (size_t)e * R * C;
  unsigned short* op = (which ? W2t : W1t) + (size_t)e * R * C;
  const int tid = threadIdx.x;

  // read: 128 rows x 32 cols fp32 (16 KB), 128B segments per row
  int rr = tid >> 3;            // 0..31
  int c4 = (tid & 7) * 4;       // 0..28
#pragma unroll
  for (int p = 0; p < 4; p++) {
    int r = p * 32 + rr;
    float4 v = *(const float4*)(ip + (size_t)(by * 128 + r) * C + bx * 32 + c4);
    tile[r][c4 + 0] = v.x; tile[r][c4 + 1] = v.y;
    tile[r][c4 + 2] = v.z; tile[r][c4 + 3] = v.w;
  }
  __syncthreads();
  // write: 32 cols, each 128 contiguous rows bf16 = 256B (16 lanes x 16B)
  int cc = tid >> 4;            // 0..15
  int r8 = (tid & 15) * 8;      // 0..120
#pragma unroll
  for (int q = 0; q < 2; q++) {
    int c = q * 16 + cc;
    unsigned short h[8];
#pragma unroll
    for (int j = 0; j < 8; j++) h[j] = f2bf(tile[r8 + j][c]);
    *(uint4*)(op + (size_t)(bx * 32 + c) * R + by * 128 + r8) = *(const uint4*)h;
  }
}

// ---------------- grouped GEMM, BK=64, XOR-swizzled LDS ----------------
// MODE 0: z=expert.            Hout[row,n] = bf16(relu(acc + bias[n]))
// MODE 1: z=e*2+half, split-K. Yout[half][row,n] = acc (+ bias if half==0)
template <int MODE, int KTOT>
__global__ __launch_bounds__(256) void moe_gemm(
    const unsigned short* __restrict__ Ain, const unsigned short* __restrict__ Bt,
    const float* __restrict__ bias, const int* __restrict__ counts,
    const int* __restrict__ offsets,
    unsigned short* __restrict__ Hout, float* __restrict__ Yout,
    int lda, int ldb, int N) {
  int e, half;
  if (MODE == 0) { e = blockIdx.z; half = 0; }
  else           { e = blockIdx.z >> 1; half = blockIdx.z & 1; }
  const int cnt = counts[e];
  int mt_, nt_;
  if (MODE == 0) {
    // XCD-aware remap: x&7 ~ XCD id keeps few B n-tiles L2-resident
    nt_ = (blockIdx.x & 7) | ((blockIdx.y & 3) << 3);
    mt_ = (blockIdx.x >> 3) | ((blockIdx.y >> 2) << 2);
  } else {
    nt_ = blockIdx.x; mt_ = blockIdx.y;
  }
  const int m0 = mt_ * 128;
  if (m0 >= cnt) return;
  const int n0 = nt_ * 128;
  const int rowbase = offsets[e];
  const unsigned short* A = Ain + (size_t)half * KTOT;   // split-K offset within row

  __shared__ unsigned short sh[2 * 128 * 64];   // As | Bs, 32 KB
  unsigned short* As = sh;
  unsigned short* Bs = sh + 128 * 64;

  const int tid = threadIdx.x;
  const int w = tid >> 6;
  const int lane = tid & 63;
  const int l15 = lane & 15, l4 = lane >> 4;
  const int wm = w >> 1, wn = w & 1;
  const int lrow = lane >> 3, lslot = lane & 7;
  const int lchunk = lslot ^ lrow;   // XOR swizzle

  const unsigned short* gA[4]; const unsigned short* gB[4];
  void* dA[4]; void* dB[4];
  const unsigned short* Bbase = Bt + (size_t)e * N * ldb + (size_t)half * KTOT;
#pragma unroll
  for (int p = 0; p < 4; p++) {
    int rw = p * 32 + w * 8;
    gA[p] = A + (size_t)(rowbase + m0 + rw + lrow) * lda + lchunk * 8;
    gB[p] = Bbase + (size_t)(n0 + rw + lrow) * ldb + lchunk * 8;
    dA[p] = (char*)As + rw * 128;
    dB[p] = (char*)Bs + rw * 128;
  }

  floatx4 acc[4][4];
#pragma unroll
  for (int i = 0; i < 4; i++)
#pragma unroll
    for (int j = 0; j < 4; j++) acc[i][j] = (floatx4){0.f, 0.f, 0.f, 0.f};

  int arow[4], brow[4], sl[2];
  sl[0] = ((l4 + 0) ^ (l15 & 7)) * 8;
  sl[1] = ((l4 + 4) ^ (l15 & 7)) * 8;
#pragma unroll
  for (int mt = 0; mt < 4; mt++) arow[mt] = (wm * 64 + mt * 16 + l15) * 64;
#pragma unroll
  for (int nt = 0; nt < 4; nt++) brow[nt] = (wn * 64 + nt * 16 + l15) * 64;

  for (int k0 = 0; k0 < KTOT; k0 += 64) {
    __syncthreads();
#pragma unroll
    for (int p = 0; p < 4; p++) async_copy16(gA[p], dA[p]);
#pragma unroll
    for (int p = 0; p < 4; p++) async_copy16(gB[p], dB[p]);
#pragma unroll
    for (int p = 0; p < 4; p++) { gA[p] += 64; gB[p] += 64; }
    __syncthreads();
#pragma unroll
    for (int s = 0; s < 2; s++) {
      short8 a[4], b[4];
#pragma unroll
      for (int mt = 0; mt < 4; mt++) a[mt] = *(const short8*)(As + arow[mt] + sl[s]);
#pragma unroll
      for (int nt = 0; nt < 4; nt++) b[nt] = *(const short8*)(Bs + brow[nt] + sl[s]);
#pragma unroll
      for (int mt = 0; mt < 4; mt++)
#pragma unroll
        for (int nt = 0; nt < 4; nt++)
          acc[mt][nt] = __builtin_amdgcn_mfma_f32_16x16x32_bf16(a[mt], b[nt], acc[mt][nt], 0, 0, 0);
    }
  }

  // ---- epilogue: per-wave-private LDS transpose -> 16B vector stores ----
  __syncthreads();                        // other waves done reading As/Bs
  float* sbuf = (float*)sh + w * 1088;    // 16 x 68 fp32, per-wave private
  const bool addb = (MODE == 0) || (half == 0);
  const float* be = bias + (size_t)e * N + n0 + wn * 64;
  float* yplane = (MODE == 1) ? (Yout + (size_t)half * MAXROWS * N) : nullptr;
#pragma unroll
  for (int mt = 0; mt < 4; mt++) {
#pragma unroll
    for (int nt = 0; nt < 4; nt++) {
      float bv = addb ? be[nt * 16 + l15] : 0.f;
#pragma unroll
      for (int r = 0; r < 4; r++) {
        float v = acc[mt][nt][r] + bv;
        if (MODE == 0) v = fmaxf(v, 0.f);
        sbuf[(l4 * 4 + r) * 68 + nt * 16 + l15] = v;
      }
    }
    __asm__ __volatile__("s_waitcnt lgkmcnt(0)" ::: "memory");  // in-wave W->R order
#pragma unroll
    for (int pass = 0; pass < 4; pass++) {
      int row = pass * 4 + l4;
      int col4 = l15 * 4;
      int gm = m0 + wm * 64 + mt * 16 + row;
      float4 v = *(const float4*)&sbuf[row * 68 + col4];
      if (gm < cnt) {
        size_t off = (size_t)(rowbase + gm) * N + n0 + wn * 64 + col4;
        if (MODE == 0) {
          ushort4 h;
          h.x = f2bf(v.x); h.y = f2bf(v.y); h.z = f2bf(v.z); h.w = f2bf(v.w);
          *(ushort4*)(Hout + off) = h;
        } else {
          *(float4*)(yplane + off) = v;
        }
      }
    }
    __asm__ __volatile__("s_waitcnt lgkmcnt(0)" ::: "memory");  // reads done before overwrite
  }
}

// ------------- combine: out[t] = (sum over splitK halves and assigned rows)/k -------------
__global__ void combine_k(const float* __restrict__ Yg, const int* __restrict__ tok2row,
                          const int* __restrict__ kptr, float* __restrict__ out) {
  int t = blockIdx.x;
  int r0 = tok2row[2 * t], r1 = tok2row[2 * t + 1];
  float invk = 1.0f / (float)kptr[0];
  int d = threadIdx.x * 4;
  const size_t plane = (size_t)MAXROWS * DIM_D;
  float4 v = *(const float4*)(Yg + (size_t)r0 * DIM_D + d);
  float4 u = *(const float4*)(Yg + plane + (size_t)r0 * DIM_D + d);
  v.x += u.x; v.y += u.y; v.z += u.z; v.w += u.w;
  if (r1 >= 0) {
    float4 a = *(const float4*)(Yg + (size_t)r1 * DIM_D + d);
    float4 b = *(const float4*)(Yg + plane + (size_t)r1 * DIM_D + d);
    v.x += a.x + b.x; v.y += a.y + b.y; v.z += a.z + b.z; v.w += a.w + b.w;
  }
  float4 o; o.x = v.x * invk; o.y = v.y * invk; o.z = v.z * invk; o.w = v.w * invk;
  *(float4*)(out + (size_t)t * DIM_D + d) = o;
}

// ---------------- launch ----------------

extern "C" void kernel_launch(void* const* d_in, const int* in_sizes, int n_in,
                              void* d_out, int out_size, void* d_ws, size_t ws_size,
                              hipStream_t stream) {
  const float* x = (const float*)d_in[0];
  const float* W1 = (const float*)d_in[1];
  const float* b1 = (const float*)d_in[2];
  const float* W2 = (const float*)d_in[3];
  const float* b2 = (const float*)d_in[4];
  const int* assign = (const int*)d_in[5];
  const int* kptr = (const int*)d_in[6];
  float* out = (float*)d_out;

  char* p = (char*)d_ws;
  int* counts = (int*)p; p += 256;
  int* offsets = (int*)p; p += 256;
  int* cursors = (int*)p; p += 256;
  int* tok2row = (int*)p; p += NUM_TOK * 2 * 4;                                // 32 KB
  unsigned short* W1t = (unsigned short*)p; p += (size_t)NUM_E * DIM_D * DIM_H * 2; // 64 MB (dead after GEMM1)
  unsigned short* Xg = (unsigned short*)p; p += (size_t)MAXROWS * DIM_D * 2;   // 17 MB (dead after GEMM1)
  unsigned short* Hg = (unsigned short*)p; p += (size_t)MAXROWS * DIM_H * 2;   // 68 MB
  unsigned short* W2t = (unsigned short*)p; p += (size_t)NUM_E * DIM_D * DIM_H * 2; // 64 MB
  // Yg (2 split-K fp32 planes, 68.2 MB) aliases dead W1t (67.1 MB) + head of Xg (17 MB)
  float* Yg = (float*)W1t;

  route_scan<<<1, 256, 0, stream>>>(assign, counts, offsets, cursors);
  gather_k<<<NUM_TOK, 128, 0, stream>>>(x, assign, cursors, tok2row, Xg);

  transpose_cvt2<<<dim3(1024, 16), 256, 0, stream>>>(W1, W2, W1t, W2t);

  // GEMM1: Hg = relu(Xg @ W1 + b1)   (K=1024, N=4096)
  moe_gemm<0, DIM_D><<<dim3(32, 32, NUM_E), 256, 0, stream>>>(
      Xg, W1t, b1, counts, offsets, Hg, nullptr, DIM_D, DIM_D, DIM_H);
  // GEMM2 split-K=2: Yg[half] = Hg[:, half] @ W2[half] (+ b2 on half 0)  (Khalf=2048, N=1024)
  moe_gemm<1, DIM_H / 2><<<dim3(8, 32, NUM_E * 2), 256, 0, stream>>>(
      Hg, W2t, b2, counts, offsets, nullptr, Yg, DIM_H, DIM_H, DIM_D);

  combine_k<<<NUM_TOK, 256, 0, stream>>>(Yg, tok2row, kptr, out);
}

// Round 5
// 556.723 us; speedup vs baseline: 1.3301x; 1.1392x over previous
//
#include <hip/hip_runtime.h>
#include <hip/hip_bf16.h>

// Problem constants: B=4, S=1024, D=1024, H=4096, E=8, K=2
#define DIM_D 1024
#define DIM_H 4096
#define NUM_E 8
#define NUM_TOK 4096
#define MAXROWS 8320           // 2*NUM_TOK assignments + tile overrun pad

typedef __attribute__((ext_vector_type(8))) short short8;
typedef __attribute__((ext_vector_type(4))) float floatx4;

__device__ __forceinline__ unsigned short f2bf(float f) {
  union { float f; unsigned int u; } v; v.f = f;
  unsigned int r = v.u + 0x7fffu + ((v.u >> 16) & 1u);   // RNE
  return (unsigned short)(r >> 16);
}

__device__ __forceinline__ void async_copy16(const void* g, void* l) {
  __builtin_amdgcn_global_load_lds(
      (__attribute__((address_space(1))) unsigned int*)(g),
      (__attribute__((address_space(3))) unsigned int*)(l), 16, 0, 0);
}

// ------------- routing: histogram + scan + deterministic row ranks, one block -------------
// 256 threads x 16 tokens = 4096 tokens exactly.
__global__ __launch_bounds__(256) void route_scan(
    const int* __restrict__ assign, int* __restrict__ counts,
    int* __restrict__ offsets, int* __restrict__ tok2row) {
  __shared__ int hist[256][NUM_E];   // 8 KB
  __shared__ int base[NUM_E];
  const int tid = threadIdx.x;
  const int t0 = tid * 16;           // 16 tokens per thread
#pragma unroll
  for (int e = 0; e < NUM_E; e++) hist[tid][e] = 0;
  const int4* ap = (const int4*)(assign + t0 * 2);   // 32 ints = 8 int4
  // count (dedup within token)
  for (int i = 0; i < 8; i++) {
    int4 v = ap[i];
    hist[tid][v.x]++; if (v.y != v.x) hist[tid][v.y]++;
    hist[tid][v.z]++; if (v.w != v.z) hist[tid][v.w]++;
  }
  __syncthreads();
  // 8 serial exclusive scans over the 256 thread-counts
  if (tid < NUM_E) {
    int acc = 0;
    for (int i = 0; i < 256; i++) { int v = hist[i][tid]; hist[i][tid] = acc; acc += v; }
    base[tid] = acc;                 // per-expert total
  }
  __syncthreads();
  if (tid == 0) {
    int acc = 0;
    for (int e = 0; e < NUM_E; e++) {
      int tot = base[e];
      counts[e] = tot; offsets[e] = acc; base[e] = acc; acc += tot;
    }
  }
  __syncthreads();
#pragma unroll
  for (int e = 0; e < NUM_E; e++) hist[tid][e] += base[e];   // own row only
  // assign rows (same traversal order as the count phase)
  for (int i = 0; i < 8; i++) {
    int4 v = ap[i];
    int t = t0 + 2 * i;
    int4 o;
    o.x = hist[tid][v.x]++;
    o.y = (v.y != v.x) ? hist[tid][v.y]++ : -1;
    o.z = hist[tid][v.z]++;
    o.w = (v.w != v.z) ? hist[tid][v.w]++ : -1;
    *(int4*)(tok2row + 2 * t) = o;
  }
}

// ------------- gather: pure copy, fp32->bf16, one block per token -------------
__global__ void gather_x(const float* __restrict__ x, const int* __restrict__ tok2row,
                         unsigned short* __restrict__ Xg) {
  int t = blockIdx.x;
  int r0 = tok2row[2 * t], r1 = tok2row[2 * t + 1];
  const float4* xv = (const float4*)(x + (size_t)t * DIM_D);
  float4 v0 = xv[threadIdx.x * 2];
  float4 v1 = xv[threadIdx.x * 2 + 1];
  unsigned short h[8];
  h[0] = f2bf(v0.x); h[1] = f2bf(v0.y); h[2] = f2bf(v0.z); h[3] = f2bf(v0.w);
  h[4] = f2bf(v1.x); h[5] = f2bf(v1.y); h[6] = f2bf(v1.z); h[7] = f2bf(v1.w);
  uint4 pack = *(uint4*)h;
  *(uint4*)(Xg + (size_t)r0 * DIM_D + threadIdx.x * 8) = pack;
  if (r1 >= 0)
    *(uint4*)(Xg + (size_t)r1 * DIM_D + threadIdx.x * 8) = pack;
}

// ------------- weight transpose + cvt: 64x64 tiles, XOR-swizzled LDS -------------
// z = e*2+which. which=0: W1 [D][H] -> W1t [H][D]; which=1: W2 [H][D] -> W2t [D][H]
__global__ __launch_bounds__(256) void transpose_cvt64(
    const float* __restrict__ W1, const float* __restrict__ W2,
    unsigned short* __restrict__ W1t, unsigned short* __restrict__ W2t) {
  __shared__ float tile[64 * 64];    // 16 KB, chunk-swizzled rows
  const int z = blockIdx.y;
  const int e = z >> 1, which = z & 1;
  const int R = which ? DIM_H : DIM_D;
  const int C = which ? DIM_D : DIM_H;
  const int nbx = C / 64;
  const int bx = blockIdx.x % nbx;
  const int by = blockIdx.x / nbx;
  const float* ip = (which ? W2 : W1) + (size_t)e * R * C + (size_t)(by * 64) * C + bx * 64;
  unsigned short* op = (which ? W2t : W1t) + (size_t)e * R * C + (size_t)(bx * 64) * R + by * 64;
  const int tid = threadIdx.x;

  // phase 1: coalesced float4 reads; swizzled b128 LDS writes (slot = chunk^(r&15))
  {
    int chunk = tid & 15;
    int rb = tid >> 4;               // 0..15
#pragma unroll
    for (int p = 0; p < 4; p++) {
      int r = rb + p * 16;           // r&15 == rb
      float4 v = *(const float4*)(ip + (size_t)r * C + chunk * 4);
      int sc = chunk ^ rb;
      *(float4*)&tile[r * 64 + sc * 4] = v;
    }
  }
  __syncthreads();
  // phase 2: col c = tid&63 (r wave-uniform per read -> exactly 2 lanes/bank, free)
  {
    int c = tid & 63;
    int rb = (tid >> 6) * 8;         // 0,8,16,24
    int ch = c >> 2, cl = c & 3;
#pragma unroll
    for (int q = 0; q < 2; q++) {
      int r0 = rb + q * 32;
      unsigned short h[8];
#pragma unroll
      for (int j = 0; j < 8; j++) {
        int r = r0 + j;
        h[j] = f2bf(tile[r * 64 + ((ch ^ (r & 15)) * 4) + cl]);
      }
      *(uint4*)(op + (size_t)c * R + r0) = *(const uint4*)h;
    }
  }
}

// ---------------- grouped GEMM, BK=64, XOR-swizzled LDS ----------------
// MODE 0: z=expert.            Hout[row,n] = bf16(relu(acc + bias[n]))
// MODE 1: z=e*2+half, split-K. Yout[half][row,n] = acc (+ bias if half==0)
template <int MODE, int KTOT>
__global__ __launch_bounds__(256) void moe_gemm(
    const unsigned short* __restrict__ Ain, const unsigned short* __restrict__ Bt,
    const float* __restrict__ bias, const int* __restrict__ counts,
    const int* __restrict__ offsets,
    unsigned short* __restrict__ Hout, float* __restrict__ Yout,
    int lda, int ldb, int N) {
  int e, half;
  if (MODE == 0) { e = blockIdx.z; half = 0; }
  else           { e = blockIdx.z >> 1; half = blockIdx.z & 1; }
  const int cnt = counts[e];
  int mt_, nt_;
  if (MODE == 0) {
    nt_ = (blockIdx.x & 7) | ((blockIdx.y & 3) << 3);
    mt_ = (blockIdx.x >> 3) | ((blockIdx.y >> 2) << 2);
  } else {
    nt_ = blockIdx.x; mt_ = blockIdx.y;
  }
  const int m0 = mt_ * 128;
  if (m0 >= cnt) return;
  const int n0 = nt_ * 128;
  const int rowbase = offsets[e];
  const unsigned short* A = Ain + (size_t)half * KTOT;

  __shared__ unsigned short sh[2 * 128 * 64];   // As | Bs, 32 KB
  unsigned short* As = sh;
  unsigned short* Bs = sh + 128 * 64;

  const int tid = threadIdx.x;
  const int w = tid >> 6;
  const int lane = tid & 63;
  const int l15 = lane & 15, l4 = lane >> 4;
  const int wm = w >> 1, wn = w & 1;
  const int lrow = lane >> 3, lslot = lane & 7;
  const int lchunk = lslot ^ lrow;   // XOR swizzle

  const unsigned short* gA[4]; const unsigned short* gB[4];
  void* dA[4]; void* dB[4];
  const unsigned short* Bbase = Bt + (size_t)e * N * ldb + (size_t)half * KTOT;
#pragma unroll
  for (int p = 0; p < 4; p++) {
    int rw = p * 32 + w * 8;
    gA[p] = A + (size_t)(rowbase + m0 + rw + lrow) * lda + lchunk * 8;
    gB[p] = Bbase + (size_t)(n0 + rw + lrow) * ldb + lchunk * 8;
    dA[p] = (char*)As + rw * 128;
    dB[p] = (char*)Bs + rw * 128;
  }

  floatx4 acc[4][4];
#pragma unroll
  for (int i = 0; i < 4; i++)
#pragma unroll
    for (int j = 0; j < 4; j++) acc[i][j] = (floatx4){0.f, 0.f, 0.f, 0.f};

  int arow[4], brow[4], sl[2];
  sl[0] = ((l4 + 0) ^ (l15 & 7)) * 8;
  sl[1] = ((l4 + 4) ^ (l15 & 7)) * 8;
#pragma unroll
  for (int mt = 0; mt < 4; mt++) arow[mt] = (wm * 64 + mt * 16 + l15) * 64;
#pragma unroll
  for (int nt = 0; nt < 4; nt++) brow[nt] = (wn * 64 + nt * 16 + l15) * 64;

  for (int k0 = 0; k0 < KTOT; k0 += 64) {
    __syncthreads();
#pragma unroll
    for (int p = 0; p < 4; p++) async_copy16(gA[p], dA[p]);
#pragma unroll
    for (int p = 0; p < 4; p++) async_copy16(gB[p], dB[p]);
#pragma unroll
    for (int p = 0; p < 4; p++) { gA[p] += 64; gB[p] += 64; }
    __syncthreads();
#pragma unroll
    for (int s = 0; s < 2; s++) {
      short8 a[4], b[4];
#pragma unroll
      for (int mt = 0; mt < 4; mt++) a[mt] = *(const short8*)(As + arow[mt] + sl[s]);
#pragma unroll
      for (int nt = 0; nt < 4; nt++) b[nt] = *(const short8*)(Bs + brow[nt] + sl[s]);
#pragma unroll
      for (int mt = 0; mt < 4; mt++)
#pragma unroll
        for (int nt = 0; nt < 4; nt++)
          acc[mt][nt] = __builtin_amdgcn_mfma_f32_16x16x32_bf16(a[mt], b[nt], acc[mt][nt], 0, 0, 0);
    }
  }

  // ---- epilogue: per-wave-private LDS transpose -> 16B vector stores ----
  __syncthreads();
  float* sbuf = (float*)sh + w * 1088;
  const bool addb = (MODE == 0) || (half == 0);
  const float* be = bias + (size_t)e * N + n0 + wn * 64;
  float* yplane = (MODE == 1) ? (Yout + (size_t)half * MAXROWS * N) : nullptr;
#pragma unroll
  for (int mt = 0; mt < 4; mt++) {
#pragma unroll
    for (int nt = 0; nt < 4; nt++) {
      float bv = addb ? be[nt * 16 + l15] : 0.f;
#pragma unroll
      for (int r = 0; r < 4; r++) {
        float v = acc[mt][nt][r] + bv;
        if (MODE == 0) v = fmaxf(v, 0.f);
        sbuf[(l4 * 4 + r) * 68 + nt * 16 + l15] = v;
      }
    }
    __asm__ __volatile__("s_waitcnt lgkmcnt(0)" ::: "memory");
#pragma unroll
    for (int pass = 0; pass < 4; pass++) {
      int row = pass * 4 + l4;
      int col4 = l15 * 4;
      int gm = m0 + wm * 64 + mt * 16 + row;
      float4 v = *(const float4*)&sbuf[row * 68 + col4];
      if (gm < cnt) {
        size_t off = (size_t)(rowbase + gm) * N + n0 + wn * 64 + col4;
        if (MODE == 0) {
          ushort4 h;
          h.x = f2bf(v.x); h.y = f2bf(v.y); h.z = f2bf(v.z); h.w = f2bf(v.w);
          *(ushort4*)(Hout + off) = h;
        } else {
          *(float4*)(yplane + off) = v;
        }
      }
    }
    __asm__ __volatile__("s_waitcnt lgkmcnt(0)" ::: "memory");
  }
}

// ------------- combine: out[t] = (sum over splitK halves and assigned rows)/k -------------
__global__ void combine_k(const float* __restrict__ Yg, const int* __restrict__ tok2row,
                          const int* __restrict__ kptr, float* __restrict__ out) {
  int t = blockIdx.x;
  int r0 = tok2row[2 * t], r1 = tok2row[2 * t + 1];
  float invk = 1.0f / (float)kptr[0];
  int d = threadIdx.x * 4;
  const size_t plane = (size_t)MAXROWS * DIM_D;
  float4 v = *(const float4*)(Yg + (size_t)r0 * DIM_D + d);
  float4 u = *(const float4*)(Yg + plane + (size_t)r0 * DIM_D + d);
  v.x += u.x; v.y += u.y; v.z += u.z; v.w += u.w;
  if (r1 >= 0) {
    float4 a = *(const float4*)(Yg + (size_t)r1 * DIM_D + d);
    float4 b = *(const float4*)(Yg + plane + (size_t)r1 * DIM_D + d);
    v.x += a.x + b.x; v.y += a.y + b.y; v.z += a.z + b.z; v.w += a.w + b.w;
  }
  float4 o; o.x = v.x * invk; o.y = v.y * invk; o.z = v.z * invk; o.w = v.w * invk;
  *(float4*)(out + (size_t)t * DIM_D + d) = o;
}

// ---------------- launch ----------------

extern "C" void kernel_launch(void* const* d_in, const int* in_sizes, int n_in,
                              void* d_out, int out_size, void* d_ws, size_t ws_size,
                              hipStream_t stream) {
  const float* x = (const float*)d_in[0];
  const float* W1 = (const float*)d_in[1];
  const float* b1 = (const float*)d_in[2];
  const float* W2 = (const float*)d_in[3];
  const float* b2 = (const float*)d_in[4];
  const int* assign = (const int*)d_in[5];
  const int* kptr = (const int*)d_in[6];
  float* out = (float*)d_out;

  char* p = (char*)d_ws;
  int* counts = (int*)p; p += 256;
  int* offsets = (int*)p; p += 256;
  int* tok2row = (int*)p; p += NUM_TOK * 2 * 4;                                // 32 KB
  unsigned short* W1t = (unsigned short*)p; p += (size_t)NUM_E * DIM_D * DIM_H * 2; // 64 MB (dead after GEMM1)
  unsigned short* Xg = (unsigned short*)p; p += (size_t)MAXROWS * DIM_D * 2;   // 17 MB (dead after GEMM1)
  unsigned short* Hg = (unsigned short*)p; p += (size_t)MAXROWS * DIM_H * 2;   // 68 MB
  unsigned short* W2t = (unsigned short*)p; p += (size_t)NUM_E * DIM_D * DIM_H * 2; // 64 MB
  // Yg (2 split-K fp32 planes, 68.2 MB) aliases dead W1t (67.1 MB) + head of Xg
  float* Yg = (float*)W1t;

  route_scan<<<1, 256, 0, stream>>>(assign, counts, offsets, tok2row);
  gather_x<<<NUM_TOK, 128, 0, stream>>>(x, tok2row, Xg);

  transpose_cvt64<<<dim3(1024, 16), 256, 0, stream>>>(W1, W2, W1t, W2t);

  // GEMM1: Hg = relu(Xg @ W1 + b1)   (K=1024, N=4096)
  moe_gemm<0, DIM_D><<<dim3(32, 32, NUM_E), 256, 0, stream>>>(
      Xg, W1t, b1, counts, offsets, Hg, nullptr, DIM_D, DIM_D, DIM_H);
  // GEMM2 split-K=2: Yg[half] = Hg[:, half] @ W2[half] (+ b2 on half 0)  (Khalf=2048, N=1024)
  moe_gemm<1, DIM_H / 2><<<dim3(8, 32, NUM_E * 2), 256, 0, stream>>>(
      Hg, W2t, b2, counts, offsets, nullptr, Yg, DIM_H, DIM_H, DIM_D);

  combine_k<<<NUM_TOK, 256, 0, stream>>>(Yg, tok2row, kptr, out);
}